// Round 5
// baseline (145.948 us; speedup 1.0000x reference)
//
#include <hip/hip_runtime.h>

using f32x4 = __attribute__((ext_vector_type(4))) float;
using s16x8 = __attribute__((ext_vector_type(8))) short;

constexpr int B = 4, T = 1024, H = 12, D = 64;
constexpr int LDK = 72;    // proj LDS stride (bf16)
constexpr int LDP = 72;    // attn P-tile stride (bf16)

__device__ __forceinline__ short f2bf(float f) {        // RNE
    unsigned u = __float_as_uint(f);
    u = (u + 0x7fffu + ((u >> 16) & 1u)) >> 16;
    return (short)u;
}
__device__ __forceinline__ short f2bf_trunc(float f) {  // truncate (p >= 0)
    return (short)(__float_as_uint(f) >> 16);
}

// ---------------------------------------------------------------------------
// Kernel 0: W prep. wt_ws[h][o][i] = W[route(h)][i][o] * (o<64 ? 0.125*log2e : 1)
// LDS-tiled transpose: coalesced read (along o) and write (along i).
// ---------------------------------------------------------------------------
__global__ __launch_bounds__(256) void wprep_kernel(
    const float* __restrict__ W, const int* __restrict__ s2h,
    short* __restrict__ wt_ws)
{
    __shared__ float tile[64][68];
    const int h = blockIdx.x, ot = blockIdx.y;          // (12, 3)
    const int kk = h >> 2, m = s2h[h];
    const float* Wp = W + (size_t)(kk * 4 + m) * D * 192 + ot * 64;
    const float qs = (ot == 0) ? 0.125f * 1.44269504f : 1.0f;
    const int tid = threadIdx.x;
    for (int e = tid; e < 1024; e += 256) {             // 64 i-rows x 16 float4
        const int i = e >> 4, o4 = e & 15;
        float4 v = *reinterpret_cast<const float4*>(Wp + (size_t)i * 192 + o4 * 4);
        tile[i][o4 * 4 + 0] = v.x * qs;
        tile[i][o4 * 4 + 1] = v.y * qs;
        tile[i][o4 * 4 + 2] = v.z * qs;
        tile[i][o4 * 4 + 3] = v.w * qs;
    }
    __syncthreads();
    short* op = wt_ws + (size_t)h * 192 * 64 + (size_t)ot * 64 * 64;
    for (int e = tid; e < 1024; e += 256) {             // 64 o-rows x 16 short4
        const int o = e >> 4, i4 = e & 15;
        short4 s = make_short4(f2bf(tile[i4 * 4 + 0][o]), f2bf(tile[i4 * 4 + 1][o]),
                               f2bf(tile[i4 * 4 + 2][o]), f2bf(tile[i4 * 4 + 3][o]));
        *reinterpret_cast<short4*>(op + o * 64 + i4 * 4) = s;
    }
}

// ---------------------------------------------------------------------------
// Kernel 1: routed QKV projection, MFMA.
// q -> [bh][T][64] (pre-scaled by 0.125*log2e via wprep), k -> [bh][T][64],
// v -> TRANSPOSED [bh][64][T]. All bf16.
// ---------------------------------------------------------------------------
__global__ __launch_bounds__(256) void proj_kernel(
    const float* __restrict__ x, const short* __restrict__ wt_ws,
    short* __restrict__ qw, short* __restrict__ kw, short* __restrict__ vt)
{
    __shared__ short ax[64 * LDK];    //  9216 B : x tile [t_loc][i]
    __shared__ short wt[192 * LDK];   // 27648 B : W^T    [o][i]
    const int h = blockIdx.y;
    const int tid = threadIdx.x;
    const int t0g = blockIdx.x * 64;
    const int b = t0g / T, t0 = t0g % T;
    const int bh = b * H + h;

    const float* xp = x + ((size_t)(b * T + t0) * H + h) * D;
    for (int e4 = tid; e4 < 64 * 16; e4 += 256) {
        const int row = e4 >> 4, i4 = e4 & 15;
        float4 v = *reinterpret_cast<const float4*>(xp + (size_t)row * H * D + i4 * 4);
        *reinterpret_cast<short4*>(&ax[row * LDK + i4 * 4]) =
            make_short4(f2bf(v.x), f2bf(v.y), f2bf(v.z), f2bf(v.w));
    }
    const short* wtp = wt_ws + (size_t)h * 192 * 64;
    for (int e8 = tid; e8 < 192 * 8; e8 += 256) {
        const int row = e8 >> 3, c8 = e8 & 7;
        *reinterpret_cast<uint4*>(&wt[row * LDK + c8 * 8]) =
            *reinterpret_cast<const uint4*>(wtp + (size_t)row * 64 + c8 * 8);
    }
    __syncthreads();

    const int wv = tid >> 6, lane = tid & 63, quad = lane >> 4, c = lane & 15;
    s16x8 af[4][2];
    #pragma unroll
    for (int mb = 0; mb < 4; ++mb)
        #pragma unroll
        for (int ks = 0; ks < 2; ++ks)
            af[mb][ks] = *reinterpret_cast<const s16x8*>(
                &ax[(mb * 16 + c) * LDK + ks * 32 + quad * 8]);

    f32x4 acc[4][3];
    #pragma unroll
    for (int mb = 0; mb < 4; ++mb)
        #pragma unroll
        for (int nb = 0; nb < 3; ++nb)
            acc[mb][nb] = (f32x4){0.f, 0.f, 0.f, 0.f};

    #pragma unroll
    for (int nb = 0; nb < 3; ++nb) {
        const int o16 = nb * 4 + wv;
        #pragma unroll
        for (int ks = 0; ks < 2; ++ks) {
            s16x8 bf = *reinterpret_cast<const s16x8*>(
                &wt[(o16 * 16 + c) * LDK + ks * 32 + quad * 8]);
            #pragma unroll
            for (int mb = 0; mb < 4; ++mb)
                acc[mb][nb] = __builtin_amdgcn_mfma_f32_16x16x32_bf16(
                    af[mb][ks], bf, acc[mb][nb], 0, 0, 0);
        }
    }

    const int d = wv * 16 + c;
    #pragma unroll
    for (int mb = 0; mb < 4; ++mb) {
        const int t = t0 + mb * 16 + quad * 4;
        #pragma unroll
        for (int reg = 0; reg < 4; ++reg) {
            qw[((size_t)bh * T + t + reg) * D + d] = f2bf(acc[mb][0][reg]);
            kw[((size_t)bh * T + t + reg) * D + d] = f2bf(acc[mb][1][reg]);
        }
        short4 s = make_short4(f2bf(acc[mb][2][0]), f2bf(acc[mb][2][1]),
                               f2bf(acc[mb][2][2]), f2bf(acc[mb][2][3]));
        *reinterpret_cast<short4*>(vt + ((size_t)bh * 64 + d) * T + t) = s;
    }
}

// ---------------------------------------------------------------------------
// Kernel 2: causal attention, MFMA, static-max base-2 softmax (p = 2^(s'-8)),
// zero barriers, no K/V LDS staging (B-frags direct from L1/L2), l via
// ones-column MFMA. Block = 2 waves x 32 q-rows; chunk = 64 k-cols.
// ---------------------------------------------------------------------------
__global__ __launch_bounds__(128) void attn_kernel(
    const short* __restrict__ qw, const short* __restrict__ kw,
    const short* __restrict__ vt, float* __restrict__ out)
{
    __shared__ short lp[2][32 * LDP];     // 9216 B, wave-private P tiles

    const int idx = blockIdx.x;
    // swizzle: same bh -> same XCD slot (idx%8), heavy qtiles dispatched first
    const int bh = (idx >> 7) * 8 + (idx & 7);
    const int qt = 15 - ((idx >> 3) & 15);
    const int b = bh / H, h = bh % H;
    const int tid = threadIdx.x, wv = tid >> 6, lane = tid & 63;
    const int quad = lane >> 4, c = lane & 15;
    const int r0 = qt * 64 + wv * 32;

    // Q A-fragments: A[m=c][k=8*quad+j] per 32-wide ks half — contiguous 16B
    s16x8 qf[2][2];
    {
        const short* qp = qw + ((size_t)bh * T + r0) * D;
        #pragma unroll
        for (int rb = 0; rb < 2; ++rb)
            #pragma unroll
            for (int ks = 0; ks < 2; ++ks)
                qf[rb][ks] = *reinterpret_cast<const s16x8*>(
                    qp + (size_t)(rb * 16 + c) * D + ks * 32 + quad * 8);
    }

    f32x4 oacc[2][4], lacc[2];
    #pragma unroll
    for (int rb = 0; rb < 2; ++rb) {
        #pragma unroll
        for (int cb = 0; cb < 4; ++cb) oacc[rb][cb] = (f32x4){0.f, 0.f, 0.f, 0.f};
        lacc[rb] = (f32x4){0.f, 0.f, 0.f, 0.f};
    }
    s16x8 lones;               // ones-column B-frag: B[k][0]=1, cols 1..15 = 0
    #pragma unroll
    for (int j = 0; j < 8; ++j) lones[j] = (c == 0) ? (short)0x3F80 : (short)0;

    const short* kbase = kw + (size_t)bh * T * D;
    const short* vbase = vt + (size_t)bh * D * T;
    short* lpw = lp[wv];

    const int nch = qt + 1;
    for (int ch = 0; ch < nch; ++ch) {
        const int sb = ch * 64;
        const bool diag = (ch == qt);

        // S' = QK^T (pre-scaled to base-2) + exp2 + P->LDS (bf16)
        #pragma unroll 4
        for (int cb = 0; cb < 4; ++cb) {
            const short* kr = kbase + (size_t)(sb + cb * 16 + c) * D;
            s16x8 kf0 = *reinterpret_cast<const s16x8*>(kr + quad * 8);
            s16x8 kf1 = *reinterpret_cast<const s16x8*>(kr + 32 + quad * 8);
            f32x4 s0 = (f32x4){0.f, 0.f, 0.f, 0.f};
            f32x4 s1 = (f32x4){0.f, 0.f, 0.f, 0.f};
            s0 = __builtin_amdgcn_mfma_f32_16x16x32_bf16(qf[0][0], kf0, s0, 0, 0, 0);
            s0 = __builtin_amdgcn_mfma_f32_16x16x32_bf16(qf[0][1], kf1, s0, 0, 0, 0);
            s1 = __builtin_amdgcn_mfma_f32_16x16x32_bf16(qf[1][0], kf0, s1, 0, 0, 0);
            s1 = __builtin_amdgcn_mfma_f32_16x16x32_bf16(qf[1][1], kf1, s1, 0, 0, 0);
            const int col = sb + cb * 16 + c;
            #pragma unroll
            for (int reg = 0; reg < 4; ++reg) {
                float v0 = s0[reg], v1 = s1[reg];
                if (diag) {
                    const int row0 = r0 + quad * 4 + reg;
                    if (col > row0)      v0 = -1e30f;
                    if (col > row0 + 16) v1 = -1e30f;
                }
                lpw[(quad * 4 + reg) * LDP + cb * 16 + c] =
                    f2bf_trunc(__builtin_amdgcn_exp2f(v0 - 8.0f));
                lpw[(16 + quad * 4 + reg) * LDP + cb * 16 + c] =
                    f2bf_trunc(__builtin_amdgcn_exp2f(v1 - 8.0f));
            }
        }

        // O += P V ; l += P*1. Same-wave DS in-order: no barrier.
        #pragma unroll
        for (int ks2 = 0; ks2 < 2; ++ks2) {
            s16x8 pa0 = *reinterpret_cast<const s16x8*>(
                &lpw[c * LDP + ks2 * 32 + quad * 8]);
            s16x8 pa1 = *reinterpret_cast<const s16x8*>(
                &lpw[(16 + c) * LDP + ks2 * 32 + quad * 8]);
            #pragma unroll
            for (int cb = 0; cb < 4; ++cb) {
                s16x8 vf = *reinterpret_cast<const s16x8*>(
                    vbase + (size_t)(cb * 16 + c) * T + sb + ks2 * 32 + quad * 8);
                oacc[0][cb] = __builtin_amdgcn_mfma_f32_16x16x32_bf16(pa0, vf, oacc[0][cb], 0, 0, 0);
                oacc[1][cb] = __builtin_amdgcn_mfma_f32_16x16x32_bf16(pa1, vf, oacc[1][cb], 0, 0, 0);
            }
            lacc[0] = __builtin_amdgcn_mfma_f32_16x16x32_bf16(pa0, lones, lacc[0], 0, 0, 0);
            lacc[1] = __builtin_amdgcn_mfma_f32_16x16x32_bf16(pa1, lones, lacc[1], 0, 0, 0);
        }
    }

    // l lives in lanes c==0 (col 0); broadcast within each quad's 16 lanes
    float linv[2][4];
    #pragma unroll
    for (int rb = 0; rb < 2; ++rb)
        #pragma unroll
        for (int reg = 0; reg < 4; ++reg)
            linv[rb][reg] = 1.0f / __shfl(lacc[rb][reg], lane & 48);

    #pragma unroll
    for (int rb = 0; rb < 2; ++rb)
        #pragma unroll
        for (int cb = 0; cb < 4; ++cb)
            #pragma unroll
            for (int reg = 0; reg < 4; ++reg) {
                const int t = r0 + rb * 16 + quad * 4 + reg;
                const int d = cb * 16 + c;
                out[((size_t)(b * T + t) * H + h) * D + d] =
                    oacc[rb][cb][reg] * linv[rb][reg];
            }
}

extern "C" void kernel_launch(void* const* d_in, const int* in_sizes, int n_in,
                              void* d_out, int out_size, void* d_ws, size_t ws_size,
                              hipStream_t stream) {
    const float* x   = (const float*)d_in[0];   // [B,T,K,N,D] fp32
    const float* W   = (const float*)d_in[1];   // [K,N,D,3D] fp32
    const int*   s2h = (const int*)d_in[2];     // [K,N] int32
    float* out = (float*)d_out;                 // [B,T,K,N,D] fp32

    short* wt_ws = (short*)d_ws;                       // [12][192][64] bf16
    short* qw    = wt_ws + (size_t)12 * 192 * 64;      // [bh][T][64] (pre-scaled)
    short* kw    = qw + (size_t)B * H * T * D;         // [bh][T][64]
    short* vt    = kw + (size_t)B * H * T * D;         // [bh][64][T]

    wprep_kernel<<<dim3(H, 3), 256, 0, stream>>>(W, s2h, wt_ws);
    proj_kernel<<<dim3(B * T / 64, H), 256, 0, stream>>>(x, wt_ws, qw, kw, vt);
    attn_kernel<<<dim3((T / 64) * (B * H)), 128, 0, stream>>>(qw, kw, vt, out);
}

// Round 7
// 108.333 us; speedup vs baseline: 1.3472x; 1.3472x over previous
//
#include <hip/hip_runtime.h>

using f32x4 = __attribute__((ext_vector_type(4))) float;
using s16x8 = __attribute__((ext_vector_type(8))) short;

constexpr int B = 4, T = 1024, H = 12, D = 64;
constexpr int LD = 72;   // LDS row stride (bf16 elems): 144B -> 2-way bank aliasing (free), 16B-aligned

__device__ __forceinline__ short f2bf(float f) {        // RNE
    unsigned u = __float_as_uint(f);
    u = (u + 0x7fffu + ((u >> 16) & 1u)) >> 16;
    return (short)u;
}
__device__ __forceinline__ short f2bf_trunc(float f) {  // truncate (p >= 0)
    return (short)(__float_as_uint(f) >> 16);
}

// ---------------------------------------------------------------------------
// Kernel 0: W prep. wt_ws[h][o][i] = W[route(h)][i][o] * (o<64 ? 0.125*log2e : 1)
// ---------------------------------------------------------------------------
__global__ __launch_bounds__(256) void wprep_kernel(
    const float* __restrict__ W, const int* __restrict__ s2h,
    short* __restrict__ wt_ws)
{
    __shared__ float tile[64][68];
    const int h = blockIdx.x, ot = blockIdx.y;          // (12, 3)
    const int kk = h >> 2, m = s2h[h];
    const float* Wp = W + (size_t)(kk * 4 + m) * D * 192 + ot * 64;
    const float qs = (ot == 0) ? 0.125f * 1.44269504f : 1.0f;
    const int tid = threadIdx.x;
    for (int e = tid; e < 1024; e += 256) {
        const int i = e >> 4, o4 = e & 15;
        float4 v = *reinterpret_cast<const float4*>(Wp + (size_t)i * 192 + o4 * 4);
        tile[i][o4 * 4 + 0] = v.x * qs;
        tile[i][o4 * 4 + 1] = v.y * qs;
        tile[i][o4 * 4 + 2] = v.z * qs;
        tile[i][o4 * 4 + 3] = v.w * qs;
    }
    __syncthreads();
    short* op = wt_ws + (size_t)h * 192 * 64 + (size_t)ot * 64 * 64;
    for (int e = tid; e < 1024; e += 256) {
        const int o = e >> 4, i4 = e & 15;
        short4 s = make_short4(f2bf(tile[i4 * 4 + 0][o]), f2bf(tile[i4 * 4 + 1][o]),
                               f2bf(tile[i4 * 4 + 2][o]), f2bf(tile[i4 * 4 + 3][o]));
        *reinterpret_cast<short4*>(op + o * 64 + i4 * 4) = s;
    }
}

// ---------------------------------------------------------------------------
// Kernel 1: routed QKV projection, MFMA, LDS-roundtrip epilogue for fully
// coalesced stores. q,k -> [bh][T][64]; v -> chunk-tiled transpose
// [bh][ct=16][d=64][t=64]. q pre-scaled by 0.125*log2e (via wprep).
// ---------------------------------------------------------------------------
__global__ __launch_bounds__(256) void proj_kernel(
    const float* __restrict__ x, const short* __restrict__ wt_ws,
    short* __restrict__ qw, short* __restrict__ kw, short* __restrict__ vt)
{
    __shared__ short buf[64 * LD + 192 * LD];   // 36864 B, aliased stage/epilogue
    short* ax = buf;                 // stage: x tile [t][i]
    short* wt = buf + 64 * LD;       // stage: W^T    [o][i]
    short* eq = buf;                 // epi: q [t][d]
    short* ek = buf + 64 * LD;       // epi: k [t][d]
    short* ev = buf + 128 * LD;      // epi: v [d][t]

    const int h = blockIdx.y;
    const int tid = threadIdx.x;
    const int t0g = blockIdx.x * 64;
    const int b = t0g / T, t0 = t0g % T;
    const int bh = b * H + h;
    const int ct = t0 >> 6;

    const float* xp = x + ((size_t)(b * T + t0) * H + h) * D;
    for (int e4 = tid; e4 < 64 * 16; e4 += 256) {
        const int row = e4 >> 4, i4 = e4 & 15;
        float4 v = *reinterpret_cast<const float4*>(xp + (size_t)row * H * D + i4 * 4);
        *reinterpret_cast<short4*>(&ax[row * LD + i4 * 4]) =
            make_short4(f2bf(v.x), f2bf(v.y), f2bf(v.z), f2bf(v.w));
    }
    const short* wtp = wt_ws + (size_t)h * 192 * 64;
    for (int e8 = tid; e8 < 192 * 8; e8 += 256) {
        const int row = e8 >> 3, c8 = e8 & 7;
        *reinterpret_cast<uint4*>(&wt[row * LD + c8 * 8]) =
            *reinterpret_cast<const uint4*>(wtp + (size_t)row * 64 + c8 * 8);
    }
    __syncthreads();

    const int wv = tid >> 6, lane = tid & 63, quad = lane >> 4, c = lane & 15;
    s16x8 af[4][2];
    #pragma unroll
    for (int mb = 0; mb < 4; ++mb)
        #pragma unroll
        for (int ks = 0; ks < 2; ++ks)
            af[mb][ks] = *reinterpret_cast<const s16x8*>(
                &ax[(mb * 16 + c) * LD + ks * 32 + quad * 8]);

    f32x4 acc[4][3];
    #pragma unroll
    for (int mb = 0; mb < 4; ++mb)
        #pragma unroll
        for (int nb = 0; nb < 3; ++nb)
            acc[mb][nb] = (f32x4){0.f, 0.f, 0.f, 0.f};

    #pragma unroll
    for (int nb = 0; nb < 3; ++nb) {
        const int o16 = nb * 4 + wv;             // wave handles one q, k, v slice
        #pragma unroll
        for (int ks = 0; ks < 2; ++ks) {
            s16x8 bf = *reinterpret_cast<const s16x8*>(
                &wt[(o16 * 16 + c) * LD + ks * 32 + quad * 8]);
            #pragma unroll
            for (int mb = 0; mb < 4; ++mb)
                acc[mb][nb] = __builtin_amdgcn_mfma_f32_16x16x32_bf16(
                    af[mb][ks], bf, acc[mb][nb], 0, 0, 0);
        }
    }
    __syncthreads();   // stage buffers dead; reuse LDS for epilogue

    const int d = wv * 16 + c;
    #pragma unroll
    for (int mb = 0; mb < 4; ++mb) {
        #pragma unroll
        for (int reg = 0; reg < 4; ++reg) {
            const int tl = mb * 16 + quad * 4 + reg;
            eq[tl * LD + d] = f2bf(acc[mb][0][reg]);
            ek[tl * LD + d] = f2bf(acc[mb][1][reg]);
        }
        short4 sv = make_short4(f2bf(acc[mb][2][0]), f2bf(acc[mb][2][1]),
                                f2bf(acc[mb][2][2]), f2bf(acc[mb][2][3]));
        *reinterpret_cast<short4*>(&ev[d * LD + mb * 16 + quad * 4]) = sv;
    }
    __syncthreads();

    // coalesced stores: a row is 64 shorts = 128 B = EIGHT 16B segments.
    // e -> (row = e>>3, seg = e&7), uint4 = 8 shorts at seg*8. 512 segs/array.
    for (int e = tid; e < 512; e += 256) {
        const int r = e >> 3, seg = e & 7;
        uint4 vq = *reinterpret_cast<const uint4*>(&eq[r * LD + seg * 8]);
        uint4 vk = *reinterpret_cast<const uint4*>(&ek[r * LD + seg * 8]);
        uint4 vv = *reinterpret_cast<const uint4*>(&ev[r * LD + seg * 8]);
        *reinterpret_cast<uint4*>(qw + ((size_t)bh * T + t0 + r) * 64 + seg * 8) = vq;
        *reinterpret_cast<uint4*>(kw + ((size_t)bh * T + t0 + r) * 64 + seg * 8) = vk;
        *reinterpret_cast<uint4*>(vt + (((size_t)bh * 16 + ct) * 64 + r) * 64 + seg * 8) = vv;
    }
}

// ---------------------------------------------------------------------------
// Kernel 2: causal attention. Transposed-score MFMA (S^T = K·Q^T) so P hits
// LDS as ds_write_b64 and PV A-frags read back as contiguous b128. Static-max
// base-2 softmax (p = 2^(s'-8)); l via lane-sum + 2 shuffles. K/V staged in
// LDS per 64-col chunk, shared by 4 waves (16 q-rows each).
// ---------------------------------------------------------------------------
__global__ __launch_bounds__(256) void attn_kernel(
    const short* __restrict__ qw, const short* __restrict__ kw,
    const short* __restrict__ vt, float* __restrict__ out)
{
    __shared__ short lk[64 * LD];        // K chunk   [s][d]
    __shared__ short lv[64 * LD];        // V^T chunk [d][s]
    __shared__ short lp[4][16 * LD];     // P, wave-private [r][s]

    const int idx = blockIdx.x;
    const int bh = idx % 48;
    const int qt = ((idx / 48) * 11) & 15;   // balances co-resident block triples
    const int b = bh / H, h = bh % H;
    const int tid = threadIdx.x, wv = tid >> 6, lane = tid & 63;
    const int quad = lane >> 4, c = lane & 15;
    const int r0 = qt * 64;

    // Q fragments (B-operand: rows of Q, n = c): contiguous 16B, once per block
    s16x8 qf[2];
    {
        const short* qp = qw + ((size_t)bh * T + r0 + wv * 16 + c) * 64;
        qf[0] = *reinterpret_cast<const s16x8*>(qp + quad * 8);
        qf[1] = *reinterpret_cast<const s16x8*>(qp + 32 + quad * 8);
    }

    f32x4 oacc[4];
    #pragma unroll
    for (int cb = 0; cb < 4; ++cb) oacc[cb] = (f32x4){0.f, 0.f, 0.f, 0.f};
    float l_run = 0.f;
    short* lpw = lp[wv];

    for (int ch = 0; ch <= qt; ++ch) {
        __syncthreads();
        const short* kp = kw + ((size_t)bh * T + ch * 64) * 64;
        const short* vp = vt + (((size_t)bh * 16 + ch) * 64) * 64;
        for (int e8 = tid; e8 < 512; e8 += 256) {
            const int r = e8 >> 3, c8 = e8 & 7;
            *reinterpret_cast<uint4*>(&lk[r * LD + c8 * 8]) =
                *reinterpret_cast<const uint4*>(kp + r * 64 + c8 * 8);
            *reinterpret_cast<uint4*>(&lv[r * LD + c8 * 8]) =
                *reinterpret_cast<const uint4*>(vp + r * 64 + c8 * 8);
        }
        __syncthreads();

        // S^T tiles: rows s (quad*4+reg), cols r (c). A = K rows, B = Q rows.
        const bool diag = (ch == qt);
        float lsum = 0.f;
        #pragma unroll
        for (int st = 0; st < 4; ++st) {
            s16x8 a0 = *reinterpret_cast<const s16x8*>(
                &lk[(st * 16 + c) * LD + quad * 8]);
            s16x8 a1 = *reinterpret_cast<const s16x8*>(
                &lk[(st * 16 + c) * LD + 32 + quad * 8]);
            f32x4 sacc = (f32x4){0.f, 0.f, 0.f, 0.f};
            sacc = __builtin_amdgcn_mfma_f32_16x16x32_bf16(a0, qf[0], sacc, 0, 0, 0);
            sacc = __builtin_amdgcn_mfma_f32_16x16x32_bf16(a1, qf[1], sacc, 0, 0, 0);
            if (diag) {
                #pragma unroll
                for (int reg = 0; reg < 4; ++reg)
                    if (st * 16 + quad * 4 + reg > wv * 16 + c) sacc[reg] = -1e30f;
            }
            float p0 = __builtin_amdgcn_exp2f(sacc[0] - 8.0f);
            float p1 = __builtin_amdgcn_exp2f(sacc[1] - 8.0f);
            float p2 = __builtin_amdgcn_exp2f(sacc[2] - 8.0f);
            float p3 = __builtin_amdgcn_exp2f(sacc[3] - 8.0f);
            lsum += (p0 + p1) + (p2 + p3);
            *reinterpret_cast<short4*>(&lpw[c * LD + st * 16 + quad * 4]) =
                make_short4(f2bf_trunc(p0), f2bf_trunc(p1),
                            f2bf_trunc(p2), f2bf_trunc(p3));
        }
        lsum += __shfl_xor(lsum, 16);
        lsum += __shfl_xor(lsum, 32);
        l_run += lsum;                      // full row-sum for r = wv*16 + c

        // O += P V : A = P rows (contiguous from lp), B = V^T rows
        #pragma unroll
        for (int ks2 = 0; ks2 < 2; ++ks2) {
            s16x8 pa = *reinterpret_cast<const s16x8*>(
                &lpw[c * LD + ks2 * 32 + quad * 8]);
            #pragma unroll
            for (int cb = 0; cb < 4; ++cb) {
                s16x8 bf = *reinterpret_cast<const s16x8*>(
                    &lv[(cb * 16 + c) * LD + ks2 * 32 + quad * 8]);
                oacc[cb] = __builtin_amdgcn_mfma_f32_16x16x32_bf16(
                    pa, bf, oacc[cb], 0, 0, 0);
            }
        }
    }

    // O rows are quad*4+reg; l lives at lane index (row) -> shuffle
    float linv[4];
    #pragma unroll
    for (int reg = 0; reg < 4; ++reg)
        linv[reg] = 1.0f / __shfl(l_run, quad * 4 + reg);

    #pragma unroll
    for (int cb = 0; cb < 4; ++cb)
        #pragma unroll
        for (int reg = 0; reg < 4; ++reg) {
            const int t = r0 + wv * 16 + quad * 4 + reg;
            out[((size_t)(b * T + t) * H + h) * D + cb * 16 + c] =
                oacc[cb][reg] * linv[reg];
        }
}

extern "C" void kernel_launch(void* const* d_in, const int* in_sizes, int n_in,
                              void* d_out, int out_size, void* d_ws, size_t ws_size,
                              hipStream_t stream) {
    const float* x   = (const float*)d_in[0];   // [B,T,K,N,D] fp32
    const float* W   = (const float*)d_in[1];   // [K,N,D,3D] fp32
    const int*   s2h = (const int*)d_in[2];     // [K,N] int32
    float* out = (float*)d_out;                 // [B,T,K,N,D] fp32

    short* wt_ws = (short*)d_ws;                       // [12][192][64] bf16
    short* qw    = wt_ws + (size_t)12 * 192 * 64;      // [bh][T][64] (pre-scaled)
    short* kw    = qw + (size_t)B * H * T * D;         // [bh][T][64]
    short* vt    = kw + (size_t)B * H * T * D;         // [bh][16][64][64] chunked V^T

    wprep_kernel<<<dim3(H, 3), 256, 0, stream>>>(W, s2h, wt_ws);
    proj_kernel<<<dim3(B * T / 64, H), 256, 0, stream>>>(x, wt_ws, qw, kw, vt);
    attn_kernel<<<dim3((T / 64) * (B * H)), 256, 0, stream>>>(qw, kw, vt, out);
}